// Round 1
// baseline (2984.676 us; speedup 1.0000x reference)
//
#include <hip/hip_runtime.h>
#include <math.h>

#define S_LEN 2048
#define B_SZ 8
#define D_IN 1024
#define DS_ 128
#define INV_TEMP (1.0f/1.000001f)
#define LBUF 712    // LDS floats per step slot: k@0 q@192 a@384 (16 chunks of 8, stride 12), v@576, g@704
#define NBLK 16     // 2 blocks per batch: bx&7 = batch, bx>>3 = v-half

// Relaxed workgroup barrier: orders LDS ops only (no vmcnt drain).
#define BAR_LDS() asm volatile("s_waitcnt lgkmcnt(0)\n\ts_barrier" ::: "memory")

// DPP row-butterfly sum across the 16-lane row (lanes sharing tid>>4).
#define DPPADD(x, ctrl) { int t_ = __builtin_amdgcn_update_dpp( \
    0, __float_as_int(x), ctrl, 0xF, 0xF, false); x += __int_as_float(t_); }
#define ROWSUM(x) { DPPADD(x, 0x128) DPPADD(x, 0x124) DPPADD(x, 0x122) DPPADD(x, 0x121) }

// ---------------------------------------------------------------------------
// Kernel 1: fused projection GEMM  P[16384][512] = x @ [Wk|Wv|Wq|Wa]^T
// ---------------------------------------------------------------------------
__global__ __launch_bounds__(256) void proj_gemm(
    const float* __restrict__ X,
    const float* __restrict__ Wk, const float* __restrict__ Wv,
    const float* __restrict__ Wq, const float* __restrict__ Wa,
    float* __restrict__ P)
{
    __shared__ __align__(16) float As[32][68];
    __shared__ __align__(16) float Bs[32][68];
    const int tid = threadIdx.x;
    const int m0 = blockIdx.x * 64;
    const int n0 = blockIdx.y * 64;
    const int lr = tid >> 3;
    const int lk4 = tid & 7;

    const float* wrows[2];
#pragma unroll
    for (int i = 0; i < 2; i++) {
        int nn = n0 + lr + i * 32;
        const float* w;
        if      (nn < 128) w = Wk + (size_t)nn * D_IN;
        else if (nn < 256) w = Wv + (size_t)(nn - 128) * D_IN;
        else if (nn < 384) w = Wq + (size_t)(nn - 256) * D_IN;
        else               w = Wa + (size_t)(nn - 384) * D_IN;
        wrows[i] = w;
    }
    const int ty = tid >> 4, tx = tid & 15;
    float acc[4][4];
#pragma unroll
    for (int i = 0; i < 4; i++)
#pragma unroll
        for (int j = 0; j < 4; j++) acc[i][j] = 0.f;

    for (int k0 = 0; k0 < D_IN; k0 += 32) {
#pragma unroll
        for (int i = 0; i < 2; i++) {
            int m = lr + i * 32;
            float4 a4 = *(const float4*)(X + (size_t)(m0 + m) * D_IN + k0 + lk4 * 4);
            As[lk4*4+0][m] = a4.x; As[lk4*4+1][m] = a4.y;
            As[lk4*4+2][m] = a4.z; As[lk4*4+3][m] = a4.w;
            float4 b4 = *(const float4*)(wrows[i] + k0 + lk4 * 4);
            Bs[lk4*4+0][m] = b4.x; Bs[lk4*4+1][m] = b4.y;
            Bs[lk4*4+2][m] = b4.z; Bs[lk4*4+3][m] = b4.w;
        }
        __syncthreads();
#pragma unroll
        for (int kk = 0; kk < 32; kk++) {
            float4 a4 = *(const float4*)(&As[kk][ty * 4]);
            float4 b4 = *(const float4*)(&Bs[kk][tx * 4]);
            float a[4] = {a4.x, a4.y, a4.z, a4.w};
            float b[4] = {b4.x, b4.y, b4.z, b4.w};
#pragma unroll
            for (int i = 0; i < 4; i++)
#pragma unroll
                for (int j = 0; j < 4; j++)
                    acc[i][j] = fmaf(a[i], b[j], acc[i][j]);
        }
        __syncthreads();
    }
#pragma unroll
    for (int i = 0; i < 4; i++) {
        float4 o; o.x = acc[i][0]; o.y = acc[i][1]; o.z = acc[i][2]; o.w = acc[i][3];
        *(float4*)(P + (size_t)(m0 + ty * 4 + i) * 512 + n0 + tx * 4) = o;
    }
}

// ---------------------------------------------------------------------------
// Kernel 2: postprocess per token. In-place on P: k<-l2norm(k), q<-l2norm(q),
// r-slot<-alpha. G[tok] = sum_k q_k*(1-alpha_k)*k_k.
// ---------------------------------------------------------------------------
__global__ __launch_bounds__(128) void postproc(
    float* __restrict__ P, float* __restrict__ G,
    const float* __restrict__ bA, const float* __restrict__ lam)
{
    const int tok = blockIdx.x, i = threadIdx.x;
    float* row = P + (size_t)tok * 512;
    float kr = row[i], qr = row[256 + i], rr = row[384 + i];
    float ks = kr * kr, qs = qr * qr;
#pragma unroll
    for (int m = 1; m < 64; m <<= 1) { ks += __shfl_xor(ks, m); qs += __shfl_xor(qs, m); }
    __shared__ float sb[6];
    if ((i & 63) == 0) { sb[(i >> 6) * 2] = ks; sb[(i >> 6) * 2 + 1] = qs; }
    __syncthreads();
    float kinv = 1.0f / fmaxf(sqrtf(sb[0] + sb[2]), 1e-12f);
    float qinv = 1.0f / fmaxf(sqrtf(sb[1] + sb[3]), 1e-12f);
    float kn = kr * kinv, qn = qr * qinv;
    float sr = 1.0f / (1.0f + __expf(-(rr + bA[i])));
    float sl = 1.0f / (1.0f + __expf(-lam[i]));
    float la = logf(sl + 1e-8f);
    float al = __expf(8.0f * sr * la);
    row[i] = kn; row[256 + i] = qn; row[384 + i] = al;
    float gi = qn * (1.0f - al) * kn;
#pragma unroll
    for (int m = 1; m < 64; m <<= 1) gi += __shfl_xor(gi, m);
    if ((i & 63) == 0) sb[4 + (i >> 6)] = gi;
    __syncthreads();
    if (i == 0) G[tok] = sb[4] + sb[5];
}

// ---------------------------------------------------------------------------
// Kernel 3: sequential recurrence, v-SPLIT across 2 CUs per batch.
// 16 blocks x 512 threads. Block bx: batch=bx&7, v-half=bx>>3 (blocks b and
// b+8 pair; round-robin dispatch puts them on the same XCD -> L2-local sync).
// Thread (c=tid&15, vp=tid>>4) owns H[k][v], k in [c*8,c*8+8),
// v in [half*64 + vp*2, +2). Per-step cross-block exchange: ONE float
// (partial err), via agent-scope atomics on per-(block,t) slots (value+1.0,
// 0 = not ready; slots zeroed by hipMemsetAsync each launch -> no reuse/ABA).
// Poll latency hidden by: issue store -> H decay (a*H) -> next-token LDS
// register loads, all sur-independent, THEN poll; only H += w*(sur*d) and
// the y-store depend on the peer value.
// ---------------------------------------------------------------------------
__global__ __launch_bounds__(512, 2) void recurrence(
    const float* __restrict__ P, const float* __restrict__ G,
    float* __restrict__ Y, float* __restrict__ EB)
{
    const int bx = blockIdx.x;
    const int b = bx & 7;
    const int half = bx >> 3;
    const int tid = threadIdx.x;
    const int c = tid & 15;
    const int vp = tid >> 4;      // 0..31
    const int lane = tid & 63;
    const int wave = tid >> 6;    // 0..7
    const int co = c * 12;
    const int voff = 576 + half * 64 + vp * 2;

    __shared__ __align__(16) float Pbuf[3][LBUF];
    __shared__ __align__(16) float errw[2][8];

    const float* Pb = P + (size_t)b * S_LEN * 512;
    const float* Gb = G + (size_t)b * S_LEN;
    float* Yb = Y + (size_t)b * S_LEN * DS_ + half * 64;
    float* own = EB + (size_t)bx * S_LEN;
    const float* peer = EB + (size_t)(bx ^ 8) * S_LEN;

    float2 H[8];
#pragma unroll
    for (int j = 0; j < 8; j++) { H[j].x = 0.f; H[j].y = 0.f; }

    const bool isP = tid < 256;
    const bool isG = (tid == 256);
    int spos = 0;
    if (isP) {
        int i = tid * 2, s = i >> 7, idx = i & 127, cp = (idx >> 3) * 12 + (idx & 7);
        spos = (s == 0) ? cp : (s == 1) ? (576 + idx) : (s == 2) ? (192 + cp) : (384 + cp);
    }

    float2 rp0 = {0.f, 0.f}, rp1 = {0.f, 0.f};
    float rg0 = 0.f, rg1 = 0.f;
    if (isP) { rp0 = *(const float2*)(Pb + tid * 2); rp1 = *(const float2*)(Pb + 512 + tid * 2); }
    if (isG) { rg0 = Gb[0]; rg1 = Gb[1]; }
    if (isP) *(float2*)(&Pbuf[0][spos]) = rp0;
    if (isG) Pbuf[0][704] = rg0;
    __syncthreads();

    float4 k0, k1, q0, q1, a0, a1; float2 vt; float g;
#define LOADREGS(T) { float* cb = &Pbuf[(T) % 3][0]; \
    k0 = *(const float4*)(cb + co);       k1 = *(const float4*)(cb + co + 4); \
    q0 = *(const float4*)(cb + 192 + co); q1 = *(const float4*)(cb + 192 + co + 4); \
    a0 = *(const float4*)(cb + 384 + co); a1 = *(const float4*)(cb + 384 + co + 4); \
    vt = *(const float2*)(cb + voff);     g  = cb[704]; }

    LOADREGS(0)

#define STEP(T, PAR, RPS, RGS, RPL, RGL) { \
    float kk[8] = {k0.x,k0.y,k0.z,k0.w,k1.x,k1.y,k1.z,k1.w}; \
    float qq[8] = {q0.x,q0.y,q0.z,q0.w,q1.x,q1.y,q1.z,q1.w}; \
    float aa[8] = {a0.x,a0.y,a0.z,a0.w,a1.x,a1.y,a1.z,a1.w}; \
    float zz[8], ww[8]; \
    _Pragma("unroll") for (int j = 0; j < 8; j++) { \
        zz[j] = qq[j] * aa[j]; ww[j] = fmaf(-kk[j], aa[j], kk[j]); } \
    float2 pr = {0.f,0.f}, kp = {0.f,0.f}, ya = {0.f,0.f}; \
    _Pragma("unroll") for (int j = 0; j < 8; j++) { \
        pr.x = fmaf(qq[j], H[j].x, pr.x); pr.y = fmaf(qq[j], H[j].y, pr.y); \
        kp.x = fmaf(kk[j], H[j].x, kp.x); kp.y = fmaf(kk[j], H[j].y, kp.y); \
        ya.x = fmaf(zz[j], H[j].x, ya.x); ya.y = fmaf(zz[j], H[j].y, ya.y); } \
    ROWSUM(pr.x) ROWSUM(pr.y) ROWSUM(kp.x) ROWSUM(kp.y) ROWSUM(ya.x) ROWSUM(ya.y) \
    float ex = vt.x - pr.x, ey = vt.y - pr.y; \
    float ep = fmaf(ex, ex, ey * ey); \
    ep += __shfl_xor(ep, 16); ep += __shfl_xor(ep, 32); \
    if (lane == 0) errw[PAR][wave] = ep; \
    float2 d2; d2.x = vt.x - kp.x; d2.y = vt.y - kp.y; \
    const float gcur = g; const float2 yac = ya; \
    if ((T) + 1 < S_LEN) { \
        if (isP) *(float2*)(&Pbuf[((T) + 1) % 3][spos]) = RPS; \
        if (isG) Pbuf[((T) + 1) % 3][704] = RGS; } \
    if ((T) + 2 < S_LEN) { \
        if (isP) RPL = *(const float2*)(Pb + (size_t)((T) + 2) * 512 + tid * 2); \
        if (isG) RGL = Gb[(T) + 2]; } \
    BAR_LDS(); \
    const float4 ea  = *(const float4*)(&errw[PAR][0]); \
    const float4 eb2 = *(const float4*)(&errw[PAR][4]); \
    float el = ((ea.x + ea.y) + (ea.z + ea.w)) + ((eb2.x + eb2.y) + (eb2.z + eb2.w)); \
    if (tid == 0) __hip_atomic_store(own + (T), el + 1.0f, \
        __ATOMIC_RELAXED, __HIP_MEMORY_SCOPE_AGENT); \
    _Pragma("unroll") for (int j = 0; j < 8; j++) { H[j].x *= aa[j]; H[j].y *= aa[j]; } \
    if ((T) + 1 < S_LEN) LOADREGS((T) + 1) \
    float pv; \
    do { pv = __hip_atomic_load(peer + (T), \
        __ATOMIC_RELAXED, __HIP_MEMORY_SCOPE_AGENT); } while (pv == 0.0f); \
    float err = el + (pv - 1.0f); \
    float sur = 1.0f / (1.0f + __expf(-err * INV_TEMP)); \
    float2 sd; sd.x = sur * d2.x; sd.y = sur * d2.y; \
    _Pragma("unroll") for (int j = 0; j < 8; j++) { \
        H[j].x = fmaf(ww[j], sd.x, H[j].x); H[j].y = fmaf(ww[j], sd.y, H[j].y); } \
    if (c == 0) { \
        float sg = sur * gcur; float2 y2; \
        y2.x = fmaf(sg, d2.x, yac.x); y2.y = fmaf(sg, d2.y, yac.y); \
        *(float2*)(Yb + (size_t)(T) * DS_ + vp * 2) = y2; } \
}

    for (int t = 0; t < S_LEN; t += 2) {
        STEP(t,     0, rp1, rg1, rp0, rg0)
        STEP(t + 1, 1, rp0, rg0, rp1, rg1)
    }
#undef STEP
#undef LOADREGS
}

// ---------------------------------------------------------------------------
// Kernel 4: RMSNorm over DS per token (in-place on Y)
// ---------------------------------------------------------------------------
__global__ __launch_bounds__(128) void rmsnorm(
    float* __restrict__ Y, const float* __restrict__ nw)
{
    const int tok = blockIdx.x, i = threadIdx.x;
    float y = Y[(size_t)tok * DS_ + i];
    float s = y * y;
#pragma unroll
    for (int m = 1; m < 64; m <<= 1) s += __shfl_xor(s, m);
    __shared__ float sb[2];
    if ((i & 63) == 0) sb[i >> 6] = s;
    __syncthreads();
    float ms = (sb[0] + sb[1]) * (1.0f / 128.0f);
    Y[(size_t)tok * DS_ + i] = y * rsqrtf(ms + 1e-6f) * nw[i];
}

// ---------------------------------------------------------------------------
// Kernel 5: output GEMM  Out[16384][1024] = Yn[16384][128] @ Wo[1024][128]^T
// ---------------------------------------------------------------------------
__global__ __launch_bounds__(256) void out_gemm(
    const float* __restrict__ Yn, const float* __restrict__ Wo, float* __restrict__ Out)
{
    __shared__ __align__(16) float As[32][68];
    __shared__ __align__(16) float Bs[32][68];
    const int tid = threadIdx.x;
    const int m0 = blockIdx.x * 64;
    const int n0 = blockIdx.y * 64;
    const int lr = tid >> 3;
    const int lk4 = tid & 7;
    const int ty = tid >> 4, tx = tid & 15;
    float acc[4][4];
#pragma unroll
    for (int i = 0; i < 4; i++)
#pragma unroll
        for (int j = 0; j < 4; j++) acc[i][j] = 0.f;

    for (int k0 = 0; k0 < DS_; k0 += 32) {
#pragma unroll
        for (int i = 0; i < 2; i++) {
            int m = lr + i * 32;
            float4 a4 = *(const float4*)(Yn + (size_t)(m0 + m) * DS_ + k0 + lk4 * 4);
            As[lk4*4+0][m] = a4.x; As[lk4*4+1][m] = a4.y;
            As[lk4*4+2][m] = a4.z; As[lk4*4+3][m] = a4.w;
            float4 b4 = *(const float4*)(Wo + (size_t)(n0 + m) * DS_ + k0 + lk4 * 4);
            Bs[lk4*4+0][m] = b4.x; Bs[lk4*4+1][m] = b4.y;
            Bs[lk4*4+2][m] = b4.z; Bs[lk4*4+3][m] = b4.w;
        }
        __syncthreads();
#pragma unroll
        for (int kk = 0; kk < 32; kk++) {
            float4 a4 = *(const float4*)(&As[kk][ty * 4]);
            float4 b4 = *(const float4*)(&Bs[kk][tx * 4]);
            float a[4] = {a4.x, a4.y, a4.z, a4.w};
            float b[4] = {b4.x, b4.y, b4.z, b4.w};
#pragma unroll
            for (int i = 0; i < 4; i++)
#pragma unroll
                for (int j = 0; j < 4; j++)
                    acc[i][j] = fmaf(a[i], b[j], acc[i][j]);
        }
        __syncthreads();
    }
#pragma unroll
    for (int i = 0; i < 4; i++) {
        float4 o; o.x = acc[i][0]; o.y = acc[i][1]; o.z = acc[i][2]; o.w = acc[i][3];
        *(float4*)(Out + (size_t)(m0 + ty * 4 + i) * 1024 + n0 + tx * 4) = o;
    }
}

// ---------------------------------------------------------------------------
extern "C" void kernel_launch(void* const* d_in, const int* in_sizes, int n_in,
                              void* d_out, int out_size, void* d_ws, size_t ws_size,
                              hipStream_t stream)
{
    const float* x   = (const float*)d_in[0];
    const float* Wk  = (const float*)d_in[1];
    const float* Wv  = (const float*)d_in[2];
    const float* Wq  = (const float*)d_in[3];
    const float* Waw = (const float*)d_in[4];
    const float* Wab = (const float*)d_in[5];
    const float* lam = (const float*)d_in[6];
    const float* Wo  = (const float*)d_in[7];
    const float* nw  = (const float*)d_in[8];
    float* out = (float*)d_out;

    const size_t NTOK = (size_t)B_SZ * S_LEN;   // 16384
    float* P  = (float*)d_ws;                    // NTOK*512
    float* G  = P + NTOK * 512;                  // NTOK
    float* Y  = G + NTOK;                        // NTOK*128
    float* EB = Y + NTOK * 128;                  // NBLK*S_LEN err-exchange slots

    hipMemsetAsync(EB, 0, (size_t)NBLK * S_LEN * sizeof(float), stream);
    proj_gemm<<<dim3(NTOK / 64, 512 / 64), 256, 0, stream>>>(x, Wk, Wv, Wq, Waw, P);
    postproc<<<NTOK, 128, 0, stream>>>(P, G, Wab, lam);
    recurrence<<<NBLK, 512, 0, stream>>>(P, G, Y, EB);
    rmsnorm<<<NTOK, 128, 0, stream>>>(Y, nw);
    out_gemm<<<dim3(NTOK / 64, 1024 / 64), 256, 0, stream>>>(Y, Wo, out);
}